// Round 12
// baseline (5754.864 us; speedup 1.0000x reference)
//
#include <hip/hip_runtime.h>
#include <stdint.h>

typedef _Float16 f16;
typedef __attribute__((ext_vector_type(8))) _Float16 f16x8;
typedef __attribute__((ext_vector_type(4))) float f32x4;

#define BD 64      // state dim D
#define HW 512     // hidden width W
#define TT 16      // time points T
#define BR 64      // batch rows per group (M=64)
#define NTHREADS 1024
#define NGRP 8     // batch groups (512/64)
#define NCU 8      // CUs per group (W1 split 8 ways, 64 KB LDS-resident each)

// lgkm-only barrier: LDS producer->consumer, no vmcnt drain
#define LBAR() asm volatile("s_waitcnt lgkmcnt(0)\n\ts_barrier" ::: "memory")
#define VM_DRAIN() asm volatile("s_waitcnt vmcnt(0)" ::: "memory")

// Tsit5 coefficients
constexpr float cA21 = 0.161f;
constexpr float cA31 = -0.008480655492356989f, cA32 = 0.335480655492357f;
constexpr float cA41 = 2.8971530571054935f, cA42 = -6.359448489975075f, cA43 = 4.3622954328695815f;
constexpr float cA51 = 5.325864828439257f, cA52 = -11.748883564062828f, cA53 = 7.4955393428898365f, cA54 = -0.09249506636175525f;
constexpr float cA61 = 5.86145544294642f, cA62 = -12.92096931784711f, cA63 = 8.159367898576159f, cA64 = -0.071584973281401f, cA65 = -0.028269050394068383f;
constexpr float cB1 = 0.09646076681806523f, cB2 = 0.01f, cB3 = 0.4798896504144996f;
constexpr float cB4 = 1.379008574103742f, cB5 = -3.290069515436081f, cB6 = 2.324710524099774f;

__device__ __forceinline__ float softplus_f(float x) {
  return fmaxf(x, 0.0f) + __logf(1.0f + __expf(-fabsf(x)));
}

// convert W0 [512,64], W1 [512,512], W2 [64,512] (row-major f32) to fp16 in ws
__global__ void cvt_kernel(const float* __restrict__ w0,
                           const float* __restrict__ w1,
                           const float* __restrict__ w2,
                           f16* __restrict__ wsh) {
  int i = blockIdx.x * 512 + threadIdx.x;
  if (i < 32768) wsh[i] = (f16)w0[i];
  else if (i < 294912) wsh[i] = (f16)w1[i - 32768];
  else if (i < 327680) wsh[i] = (f16)w2[i - 294912];
}

__global__ __launch_bounds__(NTHREADS)
void ode_kernel(const float* __restrict__ ts,
                const float* __restrict__ y0,
                const float* __restrict__ b0,
                const float* __restrict__ b1,
                const float* __restrict__ b2,
                const f16* __restrict__ W0h,
                const f16* __restrict__ W1h,
                const f16* __restrict__ W2h,
                float* __restrict__ out,
                float* partials,
                unsigned int* flags) {
  // resident swizzled W1 slice: 64 rows x 512 cols fp16 = 65536 B
  __shared__ __align__(16) f16 w1s[64 * HW];
  __shared__ __align__(16) f16 h0buf[BR][HW + 8];   // 66560 B
  __shared__ __align__(16) f16 h1buf[BR][64 + 8];   // 9216 B
  __shared__ __align__(16) f16 atile[BR][64 + 8];   // 9216 B
  __shared__ float hsteps[TT - 1];

  const int tid  = threadIdx.x;
  const int wave = tid >> 6;        // 0..15
  const int lane = tid & 63;
  const int m = lane & 15;          // MFMA col index
  const int g = lane >> 4;          // lane group 0..3
  const int b = blockIdx.x;
  const int grp = b & 7;            // batch group; teammates {grp, grp+8, ..., grp+56}
  const int cuj = b >> 3;           // which eighth of W1/h1/K this CU owns
  const int row0 = grp * BR;
  const int cold = tid & 63;        // this thread's output column (all 4 elems)
  // per-thread output rows: wave + i*16, i=0..3 (linear elems tid + i*1024)

  // ---- wave tiling ----
  const int l1nb = (wave & 7) * 64;   // L1: col-block base (8 blocks of 64)
  const int l1rp = (wave >> 3) * 32;  // L1: row-pair base (2 blocks of 32)
  const int rt = wave >> 2;           // L2/L3: row tile 0..3
  const int nt = wave & 3;            // L2/L3: out col tile 0..3

  // ---- loop-invariant registers ----
  f16x8 w0r[2][4];                    // 32 VGPR
#pragma unroll
  for (int kt = 0; kt < 2; ++kt)
#pragma unroll
    for (int n4 = 0; n4 < 4; ++n4)
      w0r[kt][n4] = *(const f16x8*)&W0h[(l1nb + n4 * 16 + m) * BD + kt * 32 + g * 8];
  f16x8 w2r[2];                       // 8 VGPR: W2 rows nt*16+m, K-slice cuj*64
#pragma unroll
  for (int kt = 0; kt < 2; ++kt)
    w2r[kt] = *(const f16x8*)&W2h[(nt * 16 + m) * HW + cuj * 64 + kt * 32 + g * 8];
  float bias0[4];
#pragma unroll
  for (int n4 = 0; n4 < 4; ++n4) bias0[n4] = b0[l1nb + n4 * 16 + m];
  const float bias1 = b1[cuj * 64 + nt * 16 + m];
  const float b2d = b2[cold];

  // ---- y state in registers (4 elems/thread: rows wave+16i, col cold) ----
  float yv[4];
#pragma unroll
  for (int i = 0; i < 4; ++i) {
    yv[i] = y0[(row0 + wave + i * 16) * BD + cold];
    atile[wave + i * 16][cold] = (f16)yv[i];
    if (cuj == 0) out[(row0 + wave + i * 16) * (TT * BD) + cold] = yv[i];
  }
  if (tid < TT - 1) hsteps[tid] = (ts[tid + 1] - ts[tid]) * 0.25f;

  // ---- stage resident W1 slice into LDS, XOR-swizzled: byte ^= (row&7)<<4 ----
  for (int idx = tid; idx < 64 * 64; idx += NTHREADS) {
    const int row = idx >> 6, ch = idx & 63;           // ch = 16B chunk (8 f16)
    const f16x8 v = *(const f16x8*)&W1h[(size_t)(cuj * 64 + row) * HW + ch * 8];
    *(f16x8*)((char*)w1s + row * 1024 + ((ch * 16) ^ ((row & 7) << 4))) = v;
  }
  LBAR();

  const int rsw = (m & 7) << 4;   // read-side swizzle ((nt*16+m)&7 == m&7)

  int fstep = 0;                  // completed stages
  unsigned int* const flagp = &flags[grp * 32];   // one line per group (R4 layout)

  // one MLP eval of f(atile); k distributed into KK[0..3] on every CU
  auto feval = [&](float (&KK)[4]) {
    // ---- layer 1: full h0 (replicated); 16 waves = 2 row-pairs x 8 col-blocks
#pragma unroll
    for (int rtt = 0; rtt < 2; ++rtt) {
      const int rbase = l1rp + rtt * 16;
      f32x4 acc[4] = {{0,0,0,0},{0,0,0,0},{0,0,0,0},{0,0,0,0}};
#pragma unroll
      for (int kt = 0; kt < 2; ++kt) {
        const f16x8 a = *(const f16x8*)&atile[rbase + m][kt * 32 + g * 8];
#pragma unroll
        for (int n4 = 0; n4 < 4; ++n4)
          acc[n4] = __builtin_amdgcn_mfma_f32_16x16x32_f16(a, w0r[kt][n4], acc[n4], 0, 0, 0);
      }
#pragma unroll
      for (int n4 = 0; n4 < 4; ++n4) {
        const int n = l1nb + n4 * 16 + m;
#pragma unroll
        for (int j = 0; j < 4; ++j)
          h0buf[rbase + g * 4 + j][n] = (f16)softplus_f(acc[n4][j] + bias0[n4]);
      }
    }
    LBAR();
    // ---- layer 2: 16 waves = 4 row-tiles x 4 col-tiles; W1 from resident LDS
    {
      f32x4 acc1 = {0, 0, 0, 0};
      const char* const wb = (const char*)w1s + (nt * 16 + m) * 1024;
#pragma unroll
      for (int kt = 0; kt < 16; ++kt) {
        const f16x8 a = *(const f16x8*)&h0buf[rt * 16 + m][kt * 32 + g * 8];
        const f16x8 bb = *(const f16x8*)(wb + ((kt * 64 + g * 16) ^ rsw));
        acc1 = __builtin_amdgcn_mfma_f32_16x16x32_f16(a, bb, acc1, 0, 0, 0);
      }
#pragma unroll
      for (int j = 0; j < 4; ++j)
        h1buf[rt * 16 + g * 4 + j][nt * 16 + m] = (f16)softplus_f(acc1[j] + bias1);
    }
    LBAR();
    // ---- layer 3: split-K partial (local K=64); 16 waves = 4 row x 4 col tiles
    const int par = fstep & 1;      // parity buffer for this stage
    {
      f32x4 acc3 = {0, 0, 0, 0};
#pragma unroll
      for (int kt = 0; kt < 2; ++kt) {
        const f16x8 a = *(const f16x8*)&h1buf[rt * 16 + m][kt * 32 + g * 8];
        acc3 = __builtin_amdgcn_mfma_f32_16x16x32_f16(a, w2r[kt], acc3, 0, 0, 0);
      }
      float* const pb = partials + ((size_t)((grp * 2 + par) * NCU + cuj)) * 4096;
#pragma unroll
      for (int j = 0; j < 4; ++j)
        __hip_atomic_store(&pb[(rt * 16 + g * 4 + j) * 64 + nt * 16 + m], acc3[j],
                           __ATOMIC_RELAXED, __HIP_MEMORY_SCOPE_AGENT);
    }
    VM_DRAIN();          // own partial stores at coherence point
    LBAR();              // all waves of this block drained
    ++fstep;
    if (tid == 0) {
      __hip_atomic_fetch_add(flagp, 1u, __ATOMIC_RELEASE, __HIP_MEMORY_SCOPE_AGENT);
      const unsigned int tgt = (unsigned int)NCU * (unsigned int)fstep;
      while (__hip_atomic_load(flagp, __ATOMIC_ACQUIRE, __HIP_MEMORY_SCOPE_AGENT) < tgt)
        __builtin_amdgcn_s_sleep(1);
    }
    __syncthreads();
    // gather: elems tid + i*1024 = sum of 8 CU partials (+ bias); coalesced
    const float* const q = partials + (size_t)((grp * 2 + par) * NCU) * 4096;
    float s[4] = {0.f, 0.f, 0.f, 0.f};
#pragma unroll
    for (int c = 0; c < NCU; ++c) {
#pragma unroll
      for (int i = 0; i < 4; ++i)
        s[i] += __hip_atomic_load(q + c * 4096 + tid + i * 1024,
                                  __ATOMIC_RELAXED, __HIP_MEMORY_SCOPE_AGENT);
    }
#pragma unroll
    for (int i = 0; i < 4; ++i) KK[i] = s[i] + b2d;
  };

  float k1[4], k2[4], k3[4], k4[4], k5[4], k6[4];

#define COMBINE4(EXPR)                                       \
  _Pragma("unroll")                                          \
  for (int i = 0; i < 4; ++i) {                              \
    atile[wave + i * 16][cold] = (f16)(EXPR);                \
  }                                                          \
  LBAR();

  for (int t = 0; t < TT - 1; ++t) {
    const float h = hsteps[t];
    for (int s = 0; s < 4; ++s) {
      feval(k1);
      COMBINE4(yv[i] + h * (cA21 * k1[i]))
      feval(k2);
      COMBINE4(yv[i] + h * (cA31 * k1[i] + cA32 * k2[i]))
      feval(k3);
      COMBINE4(yv[i] + h * (cA41 * k1[i] + cA42 * k2[i] + cA43 * k3[i]))
      feval(k4);
      COMBINE4(yv[i] + h * (cA51 * k1[i] + cA52 * k2[i] + cA53 * k3[i] + cA54 * k4[i]))
      feval(k5);
      COMBINE4(yv[i] + h * (cA61 * k1[i] + cA62 * k2[i] + cA63 * k3[i] + cA64 * k4[i] + cA65 * k5[i]))
      feval(k6);
#pragma unroll
      for (int i = 0; i < 4; ++i)
        yv[i] += h * (cB1 * k1[i] + cB2 * k2[i] + cB3 * k3[i] +
                      cB4 * k4[i] + cB5 * k5[i] + cB6 * k6[i]);
      COMBINE4(yv[i])
    }
    if (cuj == 0) {
#pragma unroll
      for (int i = 0; i < 4; ++i)
        out[(row0 + wave + i * 16) * (TT * BD) + (t + 1) * BD + cold] = yv[i];
    }
  }
#undef COMBINE4
}

extern "C" void kernel_launch(void* const* d_in, const int* in_sizes, int n_in,
                              void* d_out, int out_size, void* d_ws, size_t ws_size,
                              hipStream_t stream) {
  const float* ts = (const float*)d_in[0];
  const float* y0 = (const float*)d_in[1];
  const float* W0 = (const float*)d_in[2];
  const float* b0 = (const float*)d_in[3];
  const float* W1 = (const float*)d_in[4];
  const float* b1 = (const float*)d_in[5];
  const float* W2 = (const float*)d_in[6];
  const float* b2 = (const float*)d_in[7];
  // ws: [0,640K) fp16 weights | 655360: flags (4KB) | 663552: k-partials (2MB, parity x 8CU)
  f16* wsh = (f16*)d_ws;
  unsigned int* flags = (unsigned int*)((char*)d_ws + 655360);
  float* partials = (float*)((char*)d_ws + 663552);

  cvt_kernel<<<640, 512, 0, stream>>>(W0, W1, W2, wsh);
  hipMemsetAsync(flags, 0, 4096, stream);
  ode_kernel<<<NGRP * NCU, NTHREADS, 0, stream>>>(ts, y0, b0, b1, b2,
                                                  wsh, wsh + 32768, wsh + 294912,
                                                  (float*)d_out, partials, flags);
}

// Round 13
// 1628.807 us; speedup vs baseline: 3.5332x; 3.5332x over previous
//
#include <hip/hip_runtime.h>
#include <stdint.h>

typedef _Float16 f16;
typedef __attribute__((ext_vector_type(4))) _Float16 f16x4;
typedef __attribute__((ext_vector_type(8))) _Float16 f16x8;
typedef __attribute__((ext_vector_type(4))) float f32x4;

#define BD 64      // state dim D
#define HW 512     // hidden width W
#define TT 16      // time points T
#define BR 16      // batch rows per group
#define NTHREADS 512
#define NGRP 32    // batch groups (512/16)
#define NCU 4      // CUs per group (W1 split 4 ways, 128 KB LDS-resident each)

// lgkm-only barrier: LDS producer->consumer, no vmcnt drain
#define LBAR() asm volatile("s_waitcnt lgkmcnt(0)\n\ts_barrier" ::: "memory")
#define VM_DRAIN() asm volatile("s_waitcnt vmcnt(0)" ::: "memory")

// Tsit5 coefficients
constexpr float cA21 = 0.161f;
constexpr float cA31 = -0.008480655492356989f, cA32 = 0.335480655492357f;
constexpr float cA41 = 2.8971530571054935f, cA42 = -6.359448489975075f, cA43 = 4.3622954328695815f;
constexpr float cA51 = 5.325864828439257f, cA52 = -11.748883564062828f, cA53 = 7.4955393428898365f, cA54 = -0.09249506636175525f;
constexpr float cA61 = 5.86145544294642f, cA62 = -12.92096931784711f, cA63 = 8.159367898576159f, cA64 = -0.071584973281401f, cA65 = -0.028269050394068383f;
constexpr float cB1 = 0.09646076681806523f, cB2 = 0.01f, cB3 = 0.4798896504144996f;
constexpr float cB4 = 1.379008574103742f, cB5 = -3.290069515436081f, cB6 = 2.324710524099774f;

__device__ __forceinline__ float softplus_f(float x) {
  return fmaxf(x, 0.0f) + __logf(1.0f + __expf(-fabsf(x)));
}

// convert W0 [512,64], W1 [512,512], W2 [64,512] (row-major f32) to fp16 in ws
__global__ void cvt_kernel(const float* __restrict__ w0,
                           const float* __restrict__ w1,
                           const float* __restrict__ w2,
                           f16* __restrict__ wsh) {
  int i = blockIdx.x * 512 + threadIdx.x;
  if (i < 32768) wsh[i] = (f16)w0[i];
  else if (i < 294912) wsh[i] = (f16)w1[i - 32768];
  else if (i < 327680) wsh[i] = (f16)w2[i - 294912];
}

__global__ __launch_bounds__(NTHREADS)
void ode_kernel(const float* __restrict__ ts,
                const float* __restrict__ y0,
                const float* __restrict__ b0,
                const float* __restrict__ b1,
                const float* __restrict__ b2,
                const f16* __restrict__ W0h,
                const f16* __restrict__ W1h,
                const f16* __restrict__ W2h,
                float* __restrict__ out,
                float* partials,
                unsigned int* flags) {
  // resident swizzled W1 slice: 128 rows x 512 cols fp16 = 131072 B
  __shared__ __align__(16) f16 w1s[128 * HW];
  __shared__ __align__(16) f16 h0buf[BR][HW + 8];
  __shared__ __align__(16) f16 h1buf[BR][128 + 8];
  __shared__ __align__(16) f16 atile[BR][BD + 8];
  __shared__ float hsteps[TT - 1];

  const int tid  = threadIdx.x;
  const int wave = tid >> 6;
  const int lane = tid & 63;
  const int m = lane & 15;   // MFMA row/col index
  const int g = lane >> 4;   // lane group 0..3
  const int b = blockIdx.x;
  const int grp = b & 31;    // batch group; teammates {grp, grp+32, +64, +96}
  const int cuj = b >> 5;    // which quarter of W1/h1/K this CU owns
  const int row0 = grp * BR;
  const int cbase = wave * 64;  // layer-1 output-col base
  const int ntile = wave & 3;   // layer-3 output col tile (waves 0-3 compute+store)
  const int r0 = tid >> 6, d = tid & 63;   // per-thread output elems (r0,d),(r0+8,d)

  // ---- loop-invariant registers ----
  f16x8 w0r[2][4];
#pragma unroll
  for (int kt = 0; kt < 2; ++kt)
#pragma unroll
    for (int nt = 0; nt < 4; ++nt)
      w0r[kt][nt] = *(const f16x8*)&W0h[(cbase + nt * 16 + m) * BD + kt * 32 + g * 8];
  f16x8 w2r[4];  // W2 K-slice [cuj*128, +128) for out tile ntile
#pragma unroll
  for (int kt = 0; kt < 4; ++kt)
    w2r[kt] = *(const f16x8*)&W2h[(ntile * 16 + m) * HW + cuj * 128 + kt * 32 + g * 8];
  // swapped-D layout: lane holds 4 consecutive n = nt*16 + 4g + j at fixed r=m
  float bias0[4][4];
#pragma unroll
  for (int nt = 0; nt < 4; ++nt)
#pragma unroll
    for (int j = 0; j < 4; ++j) bias0[nt][j] = b0[cbase + nt * 16 + g * 4 + j];
  float bias1[4];
#pragma unroll
  for (int j = 0; j < 4; ++j) bias1[j] = b1[cuj * 128 + wave * 16 + g * 4 + j];
  const float b2d = b2[d];

  // ---- y state in registers ----
  float yreg0 = y0[(row0 + r0) * BD + d];
  float yreg1 = y0[(row0 + r0 + 8) * BD + d];
  atile[r0][d] = (f16)yreg0;
  atile[r0 + 8][d] = (f16)yreg1;
  if (cuj == 0) {
    out[(row0 + r0) * (TT * BD) + d] = yreg0;
    out[(row0 + r0 + 8) * (TT * BD) + d] = yreg1;
  }
  if (tid < TT - 1) hsteps[tid] = (ts[tid + 1] - ts[tid]) * 0.25f;

  // ---- stage resident W1 slice into LDS, XOR-swizzled: byte ^= (row&7)<<4 ----
  for (int idx = tid; idx < 128 * 64; idx += NTHREADS) {
    const int row = idx >> 6, ch = idx & 63;           // ch = 16B chunk (8 f16)
    const f16x8 v = *(const f16x8*)&W1h[(size_t)(cuj * 128 + row) * HW + ch * 8];
    *(f16x8*)((char*)w1s + row * 1024 + ((ch * 16) ^ ((row & 7) << 4))) = v;
  }
  LBAR();

  const int brow = wave * 16 + m;            // this lane's W1-slice row (local)
  const char* const w1base = (const char*)w1s + brow * 1024;
  const int rsw = (brow & 7) << 4;           // read-side swizzle

  int fstep = 0;
  unsigned int* const flagp = &flags[grp * 32];   // one line per group (R4 layout)

  // one MLP eval of f(atile); k distributed into (KA,KB) on every CU
  auto feval = [&](int st, float& KA, float& KB) {
    // ---- layer 1 (operand-swapped): D[n][r]; quad ds_write_b64 h0 stores
    {
      f32x4 acc[4] = {{0,0,0,0},{0,0,0,0},{0,0,0,0},{0,0,0,0}};
#pragma unroll
      for (int kt = 0; kt < 2; ++kt) {
        const f16x8 a = *(const f16x8*)&atile[m][kt * 32 + g * 8];  // B-operand (atile^T)
#pragma unroll
        for (int nt = 0; nt < 4; ++nt)
          acc[nt] = __builtin_amdgcn_mfma_f32_16x16x32_f16(w0r[kt][nt], a, acc[nt], 0, 0, 0);
      }
#pragma unroll
      for (int nt = 0; nt < 4; ++nt) {
        f16x4 q;
#pragma unroll
        for (int j = 0; j < 4; ++j)
          q[j] = (f16)softplus_f(acc[nt][j] + bias0[nt][j]);
        *(f16x4*)&h0buf[m][cbase + nt * 16 + g * 4] = q;   // row r=m, 4 consecutive n
      }
    }
    LBAR();
    // ---- layer 2 (operand-swapped): W1 from resident LDS as A; quad h1 store
    {
      f32x4 acc1 = {0, 0, 0, 0};
#pragma unroll
      for (int kt = 0; kt < 16; ++kt) {
        const f16x8 a = *(const f16x8*)&h0buf[m][kt * 32 + g * 8];   // B-operand (h0^T)
        const f16x8 bb = *(const f16x8*)(w1base + ((kt * 64 + g * 16) ^ rsw));  // A-operand
        acc1 = __builtin_amdgcn_mfma_f32_16x16x32_f16(bb, a, acc1, 0, 0, 0);
      }
      f16x4 q;
#pragma unroll
      for (int j = 0; j < 4; ++j)
        q[j] = (f16)softplus_f(acc1[j] + bias1[j]);
      *(f16x4*)&h1buf[m][wave * 16 + g * 4] = q;           // row r=m, 4 consecutive n
    }
    LBAR();
    // ---- layer 3: split-K partial (local K=128); waves 0-3 only (was duplicated)
    if (wave < 4) {
      f32x4 acc3 = {0, 0, 0, 0};
#pragma unroll
      for (int kt = 0; kt < 4; ++kt) {
        const f16x8 a = *(const f16x8*)&h1buf[m][kt * 32 + g * 8];
        acc3 = __builtin_amdgcn_mfma_f32_16x16x32_f16(a, w2r[kt], acc3, 0, 0, 0);
      }
      float* const pb = partials + ((size_t)(grp * 6 + st) * 4 + cuj) * 1024;
#pragma unroll
      for (int j = 0; j < 4; ++j)
        __hip_atomic_store(&pb[(g * 4 + j) * 64 + ntile * 16 + m], acc3[j],
                           __ATOMIC_RELAXED, __HIP_MEMORY_SCOPE_AGENT);
    }
    VM_DRAIN();          // own partial stores at coherence point
    LBAR();              // all waves of this block drained
    ++fstep;
    if (tid == 0) {
      __hip_atomic_fetch_add(flagp, 1u, __ATOMIC_RELEASE, __HIP_MEMORY_SCOPE_AGENT);
      const unsigned int tgt = 4u * (unsigned int)fstep;
      while (__hip_atomic_load(flagp, __ATOMIC_ACQUIRE, __HIP_MEMORY_SCOPE_AGENT) < tgt)
        __builtin_amdgcn_s_sleep(1);
    }
    __syncthreads();
    // gather: k[tid], k[tid+512] = sum of 4 CU partials (+ bias); idx=tid (coalesced)
    const float* const q = partials + (size_t)(grp * 6 + st) * 4096;
    float s0 = 0.f, s1 = 0.f;
#pragma unroll
    for (int c = 0; c < 4; ++c) {
      s0 += __hip_atomic_load(q + c * 1024 + tid,       __ATOMIC_RELAXED, __HIP_MEMORY_SCOPE_AGENT);
      s1 += __hip_atomic_load(q + c * 1024 + tid + 512, __ATOMIC_RELAXED, __HIP_MEMORY_SCOPE_AGENT);
    }
    KA = s0 + b2d;
    KB = s1 + b2d;
  };

  float k1a, k1b, k2a, k2b, k3a, k3b, k4a, k4b, k5a, k5b, k6a, k6b;

#define PUT_ATILE(E0, E1) \
  atile[r0][d] = (f16)(E0); atile[r0 + 8][d] = (f16)(E1); LBAR();

  for (int t = 0; t < TT - 1; ++t) {
    const float h = hsteps[t];
    for (int s = 0; s < 4; ++s) {
      feval(0, k1a, k1b);
      PUT_ATILE(yreg0 + h * (cA21 * k1a), yreg1 + h * (cA21 * k1b))
      feval(1, k2a, k2b);
      PUT_ATILE(yreg0 + h * (cA31 * k1a + cA32 * k2a),
                yreg1 + h * (cA31 * k1b + cA32 * k2b))
      feval(2, k3a, k3b);
      PUT_ATILE(yreg0 + h * (cA41 * k1a + cA42 * k2a + cA43 * k3a),
                yreg1 + h * (cA41 * k1b + cA42 * k2b + cA43 * k3b))
      feval(3, k4a, k4b);
      PUT_ATILE(yreg0 + h * (cA51 * k1a + cA52 * k2a + cA53 * k3a + cA54 * k4a),
                yreg1 + h * (cA51 * k1b + cA52 * k2b + cA53 * k3b + cA54 * k4b))
      feval(4, k5a, k5b);
      PUT_ATILE(yreg0 + h * (cA61 * k1a + cA62 * k2a + cA63 * k3a + cA64 * k4a + cA65 * k5a),
                yreg1 + h * (cA61 * k1b + cA62 * k2b + cA63 * k3b + cA64 * k4b + cA65 * k5b))
      feval(5, k6a, k6b);
      yreg0 += h * (cB1 * k1a + cB2 * k2a + cB3 * k3a + cB4 * k4a + cB5 * k5a + cB6 * k6a);
      yreg1 += h * (cB1 * k1b + cB2 * k2b + cB3 * k3b + cB4 * k4b + cB5 * k5b + cB6 * k6b);
      PUT_ATILE(yreg0, yreg1)
    }
    if (cuj == 0) {
      out[(row0 + r0) * (TT * BD) + (t + 1) * BD + d] = yreg0;
      out[(row0 + r0 + 8) * (TT * BD) + (t + 1) * BD + d] = yreg1;
    }
  }
#undef PUT_ATILE
}

extern "C" void kernel_launch(void* const* d_in, const int* in_sizes, int n_in,
                              void* d_out, int out_size, void* d_ws, size_t ws_size,
                              hipStream_t stream) {
  const float* ts = (const float*)d_in[0];
  const float* y0 = (const float*)d_in[1];
  const float* W0 = (const float*)d_in[2];
  const float* b0 = (const float*)d_in[3];
  const float* W1 = (const float*)d_in[4];
  const float* b1 = (const float*)d_in[5];
  const float* W2 = (const float*)d_in[6];
  const float* b2 = (const float*)d_in[7];
  // ws: [0,640K) fp16 weights | 655360: flags (4KB) | 663552: k-partials (3MB)
  f16* wsh = (f16*)d_ws;
  unsigned int* flags = (unsigned int*)((char*)d_ws + 655360);
  float* partials = (float*)((char*)d_ws + 663552);

  cvt_kernel<<<640, 512, 0, stream>>>(W0, W1, W2, wsh);
  hipMemsetAsync(flags, 0, 4096, stream);
  ode_kernel<<<NGRP * NCU, NTHREADS, 0, stream>>>(ts, y0, b0, b1, b2,
                                                  wsh, wsh + 32768, wsh + 294912,
                                                  (float*)d_out, partials, flags);
}